// Round 2
// baseline (1874.535 us; speedup 1.0000x reference)
//
#include <hip/hip_runtime.h>

#define BATCH 64
#define SEQ   2048
#define EIN   256
#define HID   256

typedef _Float16 f16;
typedef _Float16 f16x8 __attribute__((ext_vector_type(8)));
typedef float    f32x4 __attribute__((ext_vector_type(4)));

__device__ __forceinline__ float tanh_fast(float x) {
    float ax = __builtin_fabsf(x);
    float e  = __expf(ax + ax);
    float r  = 1.0f - 2.0f * __builtin_amdgcn_rcpf(e + 1.0f);
    return __builtin_copysignf(r, x);
}

// ---------------- cast f32 -> f16, 8 elems/thread ----------------
__global__ __launch_bounds__(256) void cast_f32_f16(
    const float* __restrict__ s, f16* __restrict__ d, int n)
{
    int i = (blockIdx.x * 256 + threadIdx.x) * 8;
    if (i >= n) return;
    const float4* sp = reinterpret_cast<const float4*>(s + i);
    float4 a = sp[0], b = sp[1];
    f16x8 v = { (f16)a.x, (f16)a.y, (f16)a.z, (f16)a.w,
                (f16)b.x, (f16)b.y, (f16)b.z, (f16)b.w };
    *reinterpret_cast<f16x8*>(d + i) = v;
}

// ---------------- projection GEMM: C(M,256) = A(M,K) @ W(256,K)^T + bias ----
// BM=128, BN=128, BK=64, 256 threads (4 waves, 2x2), each wave 64x64 out.
__global__ __launch_bounds__(256, 2) void gemm_proj(
    const f16* __restrict__ A, const f16* __restrict__ W,
    const float* __restrict__ bias, f16* __restrict__ C, int K)
{
    const int tid  = threadIdx.x;
    const int wave = tid >> 6, lane = tid & 63;
    const int g    = lane >> 4, lr = lane & 15;
    const int bm   = blockIdx.x * 128;
    const int bn   = blockIdx.y * 128;
    const int wm   = (wave >> 1) * 64, wn = (wave & 1) * 64;

    __shared__ __align__(16) f16 As[128][72];
    __shared__ __align__(16) f16 Bs[128][72];

    f32x4 acc[4][4] = {};

    for (int kt = 0; kt < K; kt += 64) {
        __syncthreads();
#pragma unroll
        for (int i = 0; i < 4; ++i) {
            int c = i * 256 + tid;
            int r = c >> 3, sg = c & 7;
            *reinterpret_cast<f16x8*>(&As[r][sg * 8]) =
                *reinterpret_cast<const f16x8*>(A + (size_t)(bm + r) * K + kt + sg * 8);
            *reinterpret_cast<f16x8*>(&Bs[r][sg * 8]) =
                *reinterpret_cast<const f16x8*>(W + (size_t)(bn + r) * K + kt + sg * 8);
        }
        __syncthreads();
#pragma unroll
        for (int kf = 0; kf < 2; ++kf) {
            f16x8 af[4], bf[4];
#pragma unroll
            for (int f = 0; f < 4; ++f) {
                af[f] = *reinterpret_cast<const f16x8*>(&As[wm + f * 16 + lr][kf * 32 + g * 8]);
                bf[f] = *reinterpret_cast<const f16x8*>(&Bs[wn + f * 16 + lr][kf * 32 + g * 8]);
            }
#pragma unroll
            for (int fm = 0; fm < 4; ++fm)
#pragma unroll
                for (int fn = 0; fn < 4; ++fn)
                    acc[fm][fn] = __builtin_amdgcn_mfma_f32_16x16x32_f16(
                        af[fm], bf[fn], acc[fm][fn], 0, 0, 0);
        }
    }

#pragma unroll
    for (int fn = 0; fn < 4; ++fn) {
        float bv = bias[bn + wn + fn * 16 + lr];
#pragma unroll
        for (int fm = 0; fm < 4; ++fm) {
#pragma unroll
            for (int i = 0; i < 4; ++i) {
                int row = bm + wm + fm * 16 + g * 4 + i;
                int col = bn + wn + fn * 16 + lr;
                C[(size_t)row * 256 + col] = (f16)(acc[fm][fn][i] + bv);
            }
        }
    }
}

// ---------------- recurrent scan: one WG per (batch, direction) -------------
// 256 threads = 4 waves; wave w owns outputs n in [w*64, w*64+64).
// Whh kept in VGPRs as prebuilt MFMA B-fragments. h double-buffered in LDS.
// Each lane's output n == tid (fragment col = lane&15, fn block = lane>>4).
__global__ __launch_bounds__(256, 1) void rnn_scan(
    const f16* __restrict__ xpF, const f16* __restrict__ xpB,
    const float* __restrict__ WhhF, const float* __restrict__ bhhF,
    const float* __restrict__ WhhB, const float* __restrict__ bhhB,
    f16* __restrict__ seq_out,   // (B, SEQ, 512) f16, or nullptr
    float* __restrict__ fin_out) // (B, 512) f32, or nullptr
{
    const int blk = blockIdx.x;
    const int b   = blk >> 1, dir = blk & 1;
    const f16*   xp  = dir ? xpB : xpF;
    const float* Whh = dir ? WhhB : WhhF;
    const float* bhh = dir ? bhhB : bhhF;

    const int tid  = threadIdx.x;
    const int wave = tid >> 6, lane = tid & 63;
    const int g    = lane >> 4, lr = lane & 15;
    const int n0   = wave * 64;

    __shared__ __align__(16) f16 hbuf[2][256];

    // Preload Whh fragments: wf[fn][kf], lane holds W[n0+fn*16+lr][kf*32+g*8 .. +7]
    f16x8 wf[4][8];
#pragma unroll
    for (int fn = 0; fn < 4; ++fn) {
        const float* wr = Whh + (size_t)(n0 + fn * 16 + lr) * 256;
#pragma unroll
        for (int kf = 0; kf < 8; ++kf) {
            const float4* p = reinterpret_cast<const float4*>(wr + kf * 32 + g * 8);
            float4 x0 = p[0], x1 = p[1];
            wf[fn][kf] = (f16x8){ (f16)x0.x, (f16)x0.y, (f16)x0.z, (f16)x0.w,
                                  (f16)x1.x, (f16)x1.y, (f16)x1.z, (f16)x1.w };
        }
    }
    const float bv = bhh[tid];

    hbuf[0][tid] = (f16)0.f;
    __syncthreads();

    const size_t xbase = (size_t)b * SEQ * 256 + tid;

    // 3-deep register prefetch ring for xproj
    f16 ring[4];
#pragma unroll
    for (int r = 0; r < 3; ++r) {
        int t = dir ? (SEQ - 1 - r) : r;
        ring[r] = xp[xbase + (size_t)t * 256];
    }

    const f32x4 zf = {0.f, 0.f, 0.f, 0.f};

    for (int s4 = 0; s4 < SEQ; s4 += 4) {
#pragma unroll
        for (int u = 0; u < 4; ++u) {
            const int s = s4 + u;
            const int rd = u & 1;            // read buffer index (p folds to u&1)

            // A fragments: all lanes broadcast-read h (every MFMA A-row == h)
            f16x8 af[8];
#pragma unroll
            for (int kf = 0; kf < 8; ++kf)
                af[kf] = *reinterpret_cast<const f16x8*>(&hbuf[rd][kf * 32 + g * 8]);

            // prefetch xproj for step s+3
            if (s + 3 < SEQ) {
                int tp = dir ? (SEQ - 1 - (s + 3)) : (s + 3);
                ring[(u + 3) & 3] = xp[xbase + (size_t)tp * 256];
            }

            // matvec via MFMA: D[m][n] = sum_k h[k] * Whh[n][k] (all rows equal)
            f32x4 acc[4];
#pragma unroll
            for (int fn = 0; fn < 4; ++fn)
                acc[fn] = __builtin_amdgcn_mfma_f32_16x16x32_f16(af[0], wf[fn][0], zf, 0, 0, 0);
#pragma unroll
            for (int kf = 1; kf < 8; ++kf)
#pragma unroll
                for (int fn = 0; fn < 4; ++fn)
                    acc[fn] = __builtin_amdgcn_mfma_f32_16x16x32_f16(af[kf], wf[fn][kf], acc[fn], 0, 0, 0);

            // lane's output n == tid; select its fn block (== g) from reg 0
            float r01 = (g & 1) ? acc[1][0] : acc[0][0];
            float r23 = (g & 1) ? acc[3][0] : acc[2][0];
            float mv  = (g & 2) ? r23 : r01;

            float pre = mv + (float)ring[u & 3] + bv;
            float h   = tanh_fast(pre);
            f16 hh    = (f16)h;

            hbuf[rd ^ 1][tid] = hh;

            const int t = dir ? (SEQ - 1 - s) : s;
            if (seq_out)
                seq_out[((size_t)b * SEQ + t) * 512 + dir * 256 + tid] = hh;
            if (fin_out && s == SEQ - 1)
                fin_out[b * 512 + dir * 256 + tid] = h;

            // raw barrier (no vmcnt drain -> keeps xproj prefetch in flight)
            asm volatile("s_waitcnt lgkmcnt(0)" ::: "memory");
            __builtin_amdgcn_s_barrier();
            asm volatile("" ::: "memory");
        }
    }
}

extern "C" void kernel_launch(void* const* d_in, const int* in_sizes, int n_in,
                              void* d_out, int out_size, void* d_ws, size_t ws_size,
                              hipStream_t stream)
{
    (void)in_sizes; (void)n_in; (void)out_size; (void)ws_size;

    const float* x      = (const float*)d_in[0];
    const float* Wih_f0 = (const float*)d_in[1];
    const float* bih_f0 = (const float*)d_in[2];
    const float* Whh_f0 = (const float*)d_in[3];
    const float* bhh_f0 = (const float*)d_in[4];
    const float* Wih_b0 = (const float*)d_in[5];
    const float* bih_b0 = (const float*)d_in[6];
    const float* Whh_b0 = (const float*)d_in[7];
    const float* bhh_b0 = (const float*)d_in[8];
    const float* Wih_f1 = (const float*)d_in[9];
    const float* bih_f1 = (const float*)d_in[10];
    const float* Whh_f1 = (const float*)d_in[11];
    const float* bhh_f1 = (const float*)d_in[12];
    const float* Wih_b1 = (const float*)d_in[13];
    const float* bih_b1 = (const float*)d_in[14];
    const float* Whh_b1 = (const float*)d_in[15];
    const float* bhh_b1 = (const float*)d_in[16];

    float* out = (float*)d_out;
    char*  ws  = (char*)d_ws;

    // ws layout (bytes)
    f16* xpF  = (f16*)(ws);                      // 131072*256*2 = 67108864
    f16* xpB  = (f16*)(ws + 67108864);           // 67108864
    f16* out0 = (f16*)(ws + 134217728);          // 131072*512*2 = 134217728
    f16* x16  = (f16*)(ws + 268435456);          // 33554432*2  = 67108864
    f16* wf0  = (f16*)(ws + 335544320);          // 131072 B
    f16* wb0  = (f16*)(ws + 335544320 + 131072);
    f16* wf1  = (f16*)(ws + 335544320 + 262144); // 262144 B
    f16* wb1  = (f16*)(ws + 335544320 + 524288);

    // casts
    cast_f32_f16<<<16384, 256, 0, stream>>>(x, x16, 33554432);
    cast_f32_f16<<<32,    256, 0, stream>>>(Wih_f0, wf0, 65536);
    cast_f32_f16<<<32,    256, 0, stream>>>(Wih_b0, wb0, 65536);
    cast_f32_f16<<<64,    256, 0, stream>>>(Wih_f1, wf1, 131072);
    cast_f32_f16<<<64,    256, 0, stream>>>(Wih_b1, wb1, 131072);

    // layer 0 projections: K = 256
    gemm_proj<<<dim3(1024, 2), 256, 0, stream>>>(x16, wf0, bih_f0, xpF, 256);
    gemm_proj<<<dim3(1024, 2), 256, 0, stream>>>(x16, wb0, bih_b0, xpB, 256);

    // layer 0 scan -> out0 (B, SEQ, 512) f16
    rnn_scan<<<128, 256, 0, stream>>>(xpF, xpB, Whh_f0, bhh_f0, Whh_b0, bhh_b0,
                                      out0, nullptr);

    // layer 1 projections: K = 512 (reuse xpF/xpB)
    gemm_proj<<<dim3(1024, 2), 256, 0, stream>>>(out0, wf1, bih_f1, xpF, 512);
    gemm_proj<<<dim3(1024, 2), 256, 0, stream>>>(out0, wb1, bih_b1, xpB, 512);

    // layer 1 scan -> final hiddens into d_out
    rnn_scan<<<128, 256, 0, stream>>>(xpF, xpB, Whh_f1, bhh_f1, Whh_b1, bhh_b1,
                                      nullptr, out);
}